// Round 1
// 223.467 us; speedup vs baseline: 1.3315x; 1.3315x over previous
//
#include <hip/hip_runtime.h>

#define KNN 16
#define FSEM 32
#define LPG 4                 // 4 lanes cooperate per gaussian

__device__ __forceinline__ float sigmoidf_(float x) { return 1.0f / (1.0f + __expf(-x)); }

// q / clip(|q|,1e-12) -> row-major 3x3
__device__ __forceinline__ void quat_to_R(float qw, float qx, float qy, float qz, float* R) {
    float d = qw * qw + qx * qx + qy * qy + qz * qz;
    float inv = rsqrtf(fmaxf(d, 1e-24f));
    float w = qw * inv, x = qx * inv, y = qy * inv, z = qz * inv;
    R[0] = 1.f - 2.f * (y * y + z * z); R[1] = 2.f * (x * y - w * z); R[2] = 2.f * (x * z + w * y);
    R[3] = 2.f * (x * y + w * z); R[4] = 1.f - 2.f * (x * x + z * z); R[5] = 2.f * (y * z - w * x);
    R[6] = 2.f * (x * z - w * y); R[7] = 2.f * (y * z + w * x); R[8] = 1.f - 2.f * (x * x + y * y);
}

// ---- prepack: packed[p] = {x,y,z,pad, qw,qx,qy,qz}  (32 B, line-friendly) ----
__global__ void __launch_bounds__(256)
k_pack(const float* __restrict__ node_xyz, const float* __restrict__ node_quat,
       float* __restrict__ packed, int TM)
{
    int p = blockIdx.x * blockDim.x + threadIdx.x;
    if (p >= TM) return;
    const float* x = node_xyz + 3 * (size_t)p;
    float4 a = make_float4(x[0], x[1], x[2], 0.f);
    float4 q = reinterpret_cast<const float4*>(node_quat)[p];
    float4* dst = reinterpret_cast<float4*>(packed + 8 * (size_t)p);
    dst[0] = a;
    dst[1] = q;
}

// ---- elementwise outputs + (optionally) the fr_live epilogue ----
template<bool FR>
__global__ void __launch_bounds__(256)
k_elem(const float* __restrict__ gs_scal,
       const float* __restrict__ gs_opa,
       const float* __restrict__ feat_dc,
       const float* __restrict__ feat_rest,
       const float* __restrict__ gs_rot,
       const float* __restrict__ node_quat,
       const int*   __restrict__ attach_ind,
       const int*   __restrict__ ref_time,
       const float* __restrict__ qb_ws,
       float* __restrict__ out, int N, int M)
{
    const int n = blockIdx.x * blockDim.x + threadIdx.x;
    if (n >= N) return;
    const size_t Ns = (size_t)N, ns = (size_t)n;

    float* os = out + 12 * Ns + 3 * ns;
    os[0] = 0.1f * sigmoidf_(gs_scal[3 * ns + 0]);
    os[1] = 0.1f * sigmoidf_(gs_scal[3 * ns + 1]);
    os[2] = 0.1f * sigmoidf_(gs_scal[3 * ns + 2]);

    out[15 * Ns + ns] = sigmoidf_(gs_opa[ns]);

    float* osph = out + 16 * Ns + 12 * ns;   // 16B-aligned
    float4 v0 = make_float4(feat_dc[3 * ns + 0], feat_dc[3 * ns + 1], feat_dc[3 * ns + 2],
                            feat_rest[9 * ns + 0]);
    float4 v1 = make_float4(feat_rest[9 * ns + 1], feat_rest[9 * ns + 2],
                            feat_rest[9 * ns + 3], feat_rest[9 * ns + 4]);
    float4 v2 = make_float4(feat_rest[9 * ns + 5], feat_rest[9 * ns + 6],
                            feat_rest[9 * ns + 7], feat_rest[9 * ns + 8]);
    reinterpret_cast<float4*>(osph)[0] = v0;
    reinterpret_cast<float4*>(osph)[1] = v1;
    reinterpret_cast<float4*>(osph)[2] = v2;

    if constexpr (FR) {
        // fr_live = q2R(qb) @ (Rref @ q2R(gs_rot)); qb already scaled by invw
        // in the main kernel (fp32 subnormal guard).
        const int a  = attach_ind[n];
        const int rt = ref_time[n];
        const float4 qa = reinterpret_cast<const float4*>(node_quat)[(size_t)rt * (size_t)M + (size_t)a];
        float Rref[9];
        quat_to_R(qa.x, qa.y, qa.z, qa.w, Rref);

        const float4 qg = reinterpret_cast<const float4*>(gs_rot)[ns];
        float Rg[9];
        quat_to_R(qg.x, qg.y, qg.z, qg.w, Rg);

        float Rw[9];
#pragma unroll
        for (int i = 0; i < 3; i++)
#pragma unroll
            for (int j = 0; j < 3; j++)
                Rw[3 * i + j] = Rref[3 * i] * Rg[j] + Rref[3 * i + 1] * Rg[3 + j] + Rref[3 * i + 2] * Rg[6 + j];

        const float4 qb = reinterpret_cast<const float4*>(qb_ws)[ns];
        float Rb[9];
        quat_to_R(qb.x, qb.y, qb.z, qb.w, Rb);

        float* ofr = out + 3 * Ns + 9 * ns;
#pragma unroll
        for (int i = 0; i < 3; i++)
#pragma unroll
            for (int j = 0; j < 3; j++)
                ofr[3 * i + j] = Rb[3 * i] * Rw[j] + Rb[3 * i + 1] * Rw[3 + j] + Rb[3 * i + 2] * Rw[6 + j];
    }
}

// ---- main skinning kernel over packed (or raw) node data ----
template<bool PACKED, bool FRSPLIT>
__global__ void __launch_bounds__(256)
dynscf_kernel(const float* __restrict__ gs_xyz,
              const float* __restrict__ gs_rot,
              const float* __restrict__ node_xyz,
              const float* __restrict__ node_quat,
              const float* __restrict__ packed,
              const float* __restrict__ node_sigma,
              const float* __restrict__ node_sem,
              const int* __restrict__ attach_ind,
              const int* __restrict__ ref_time,
              const int* __restrict__ topo_knn,
              const int* __restrict__ t_ptr,
              float* __restrict__ out,
              float* __restrict__ qb_out,
              int N, int M)
{
    const int tid = blockIdx.x * blockDim.x + threadIdx.x;
    const int n   = tid >> 2;
    const int sub = tid & (LPG - 1);
    if (n >= N) return;

    const int t  = t_ptr[0];
    const int a  = attach_ind[n];
    const int rt = ref_time[n];

    const size_t base_rt = (size_t)rt * (size_t)M;
    const size_t base_t  = (size_t)t  * (size_t)M;

    // neighbor indices first so downstream gather addresses are known early
    const int4 kv = reinterpret_cast<const int4*>(topo_knn)[(size_t)a * (KNN / 4) + sub];
    const int js[4] = { kv.x, kv.y, kv.z, kv.w };

    // --- attach node @ ref time ---
    float apx, apy, apz, aqw, aqx, aqy, aqz;
    if (PACKED) {
        const float4* pk = reinterpret_cast<const float4*>(packed + (base_rt + (size_t)a) * 8);
        float4 xz = pk[0], qv = pk[1];
        apx = xz.x; apy = xz.y; apz = xz.z;
        aqw = qv.x; aqx = qv.y; aqy = qv.z; aqz = qv.w;
    } else {
        const float4 qv = *reinterpret_cast<const float4*>(node_quat + (base_rt + (size_t)a) * 4);
        const float* pa = node_xyz + (base_rt + (size_t)a) * 3;
        apx = pa[0]; apy = pa[1]; apz = pa[2];
        aqw = qv.x; aqx = qv.y; aqy = qv.z; aqz = qv.w;
    }
    float Rref[9];
    quat_to_R(aqw, aqx, aqy, aqz, Rref);

    const float gx = gs_xyz[3 * (size_t)n + 0];
    const float gy = gs_xyz[3 * (size_t)n + 1];
    const float gz = gs_xyz[3 * (size_t)n + 2];

    const float xw0 = Rref[0] * gx + Rref[1] * gy + Rref[2] * gz + apx;
    const float xw1 = Rref[3] * gx + Rref[4] * gy + Rref[5] * gz + apy;
    const float xw2 = Rref[6] * gx + Rref[7] * gy + Rref[8] * gz + apz;
    // NOTE: in FRSPLIT mode Rref is dead from here on (k_elem recomputes it).

    float wsum = 0.f, mu0 = 0.f, mu1 = 0.f, mu2 = 0.f;
    float qb0 = 0.f, qb1 = 0.f, qb2 = 0.f, qb3 = 0.f;
    float wk[4];

#pragma unroll
    for (int k = 0; k < KNN / LPG; k++) {
        const int j = js[k];

        float prx, pry, prz, rw, rx, ry, rz;
        float plx, ply, plz, lw, lx, ly, lz;
        if (PACKED) {
            const float4* pkr = reinterpret_cast<const float4*>(packed + (base_rt + (size_t)j) * 8);
            float4 xr = pkr[0], qr = pkr[1];
            prx = xr.x; pry = xr.y; prz = xr.z;
            rw = qr.x; rx = qr.y; ry = qr.z; rz = qr.w;
            const float4* pkl = reinterpret_cast<const float4*>(packed + (base_t + (size_t)j) * 8);
            float4 xl = pkl[0], ql = pkl[1];
            plx = xl.x; ply = xl.y; plz = xl.z;
            lw = ql.x; lx = ql.y; ly = ql.z; lz = ql.w;
        } else {
            const float* pr = node_xyz + (base_rt + (size_t)j) * 3;
            prx = pr[0]; pry = pr[1]; prz = pr[2];
            const float4 qr = *reinterpret_cast<const float4*>(node_quat + (base_rt + (size_t)j) * 4);
            rw = qr.x; rx = qr.y; ry = qr.z; rz = qr.w;
            const float* pl = node_xyz + (base_t + (size_t)j) * 3;
            plx = pl[0]; ply = pl[1]; plz = pl[2];
            const float4 ql = *reinterpret_cast<const float4*>(node_quat + (base_t + (size_t)j) * 4);
            lw = ql.x; lx = ql.y; ly = ql.z; lz = ql.w;
        }

        const float dx = xw0 - prx;
        const float dy = xw1 - pry;
        const float dz = xw2 - prz;
        const float dsq = dx * dx + dy * dy + dz * dz;

        const float sg = node_sigma[j];
        const float w = __expf(-dsq / (2.f * sg * sg + 1e-8f));
        wk[k] = w;

        {
            float inv = rsqrtf(fmaxf(rw * rw + rx * rx + ry * ry + rz * rz, 1e-24f));
            rw *= inv; rx *= inv; ry *= inv; rz *= inv;
        }
        {
            float inv = rsqrtf(fmaxf(lw * lw + lx * lx + ly * ly + lz * lz, 1e-24f));
            lw *= inv; lx *= inv; ly *= inv; lz *= inv;
        }
        // q_rel = q_live * conj(q_ref)
        const float qw =  lw * rw + lx * rx + ly * ry + lz * rz;
        const float qx = -lw * rx + lx * rw - ly * rz + lz * ry;
        const float qy = -lw * ry + lx * rz + ly * rw - lz * rx;
        const float qz = -lw * rz - lx * ry + ly * rx + lz * rw;

        float Rr[9];
        quat_to_R(qw, qx, qy, qz, Rr);

        const float m0 = Rr[0] * dx + Rr[1] * dy + Rr[2] * dz + plx;
        const float m1 = Rr[3] * dx + Rr[4] * dy + Rr[5] * dz + ply;
        const float m2 = Rr[6] * dx + Rr[7] * dy + Rr[8] * dz + plz;

        wsum += w;
        mu0 += w * m0; mu1 += w * m1; mu2 += w * m2;
        qb0 += w * qw; qb1 += w * qx; qb2 += w * qy; qb3 += w * qz;
    }

    // group-reduce the 8 scalar accumulators (2 rounds within the 4-lane group)
#pragma unroll
    for (int m = 1; m < LPG; m <<= 1) {
        wsum += __shfl_xor(wsum, m);
        mu0  += __shfl_xor(mu0, m);  mu1 += __shfl_xor(mu1, m);  mu2 += __shfl_xor(mu2, m);
        qb0  += __shfl_xor(qb0, m);  qb1 += __shfl_xor(qb1, m);
        qb2  += __shfl_xor(qb2, m);  qb3 += __shfl_xor(qb3, m);
    }

    const float invw = 1.f / (wsum + 1e-8f);
    const size_t Ns = (size_t)N, ns = (size_t)n;

    // --- sem: feature-sliced. Lane `sub` owns features [8*sub, 8*sub+8) and
    // walks all 16 neighbors, pulling (j, w) from the owning lane via shfl.
    // 8 accumulators/lane instead of 32; no cross-lane sem reduction needed. ---
    float sm0 = 0.f, sm1 = 0.f, sm2 = 0.f, sm3 = 0.f;
    float sm4 = 0.f, sm5 = 0.f, sm6 = 0.f, sm7 = 0.f;
    const float4* sem4 = reinterpret_cast<const float4*>(node_sem);
#pragma unroll
    for (int kk = 0; kk < KNN; kk++) {
        const int src = kk >> 2;        // lane within group that owns this neighbor
        const int idx = kk & 3;         // compile-time (loop fully unrolled)
        const int   jk = __shfl(js[idx], src, LPG);
        const float wkk = __shfl(wk[idx], src, LPG);
        const float4 v0 = sem4[(size_t)jk * (FSEM / 4) + sub * 2 + 0];
        const float4 v1 = sem4[(size_t)jk * (FSEM / 4) + sub * 2 + 1];
        sm0 += wkk * v0.x; sm1 += wkk * v0.y; sm2 += wkk * v0.z; sm3 += wkk * v0.w;
        sm4 += wkk * v1.x; sm5 += wkk * v1.y; sm6 += wkk * v1.z; sm7 += wkk * v1.w;
    }

    if (sub == 0) {
        out[3 * ns + 0] = mu0 * invw;
        out[3 * ns + 1] = mu1 * invw;
        out[3 * ns + 2] = mu2 * invw;
    } else if (sub == 1) {
        if (FRSPLIT) {
            reinterpret_cast<float4*>(qb_out)[ns] =
                make_float4(qb0 * invw, qb1 * invw, qb2 * invw, qb3 * invw);
        }
    }

    if constexpr (!FRSPLIT) {
        if (sub == 1) {
            // fr_live = q2R(qb*invw) @ (Rref @ q2R(gs_rot)); invw BEFORE q2R (fp32
            // subnormal guard — r5 bug).
            const float4 qg = *reinterpret_cast<const float4*>(gs_rot + 4 * ns);
            float Rg[9];
            quat_to_R(qg.x, qg.y, qg.z, qg.w, Rg);
            float Rw[9];
#pragma unroll
            for (int i = 0; i < 3; i++)
#pragma unroll
                for (int j = 0; j < 3; j++)
                    Rw[3 * i + j] = Rref[3 * i] * Rg[j] + Rref[3 * i + 1] * Rg[3 + j] + Rref[3 * i + 2] * Rg[6 + j];
            float Rb[9];
            quat_to_R(qb0 * invw, qb1 * invw, qb2 * invw, qb3 * invw, Rb);
            float* ofr = out + 3 * Ns + 9 * ns;
#pragma unroll
            for (int i = 0; i < 3; i++)
#pragma unroll
                for (int j = 0; j < 3; j++)
                    ofr[3 * i + j] = Rb[3 * i] * Rw[j] + Rb[3 * i + 1] * Rw[3 + j] + Rb[3 * i + 2] * Rw[6 + j];
        }
    }

    // sem_live: [28N, 60N); lane writes its own 2 float4s (features 8*sub..8*sub+7)
    float4* osem = reinterpret_cast<float4*>(out + 28 * Ns + FSEM * ns);
    osem[sub * 2 + 0] = make_float4(sm0 * invw, sm1 * invw, sm2 * invw, sm3 * invw);
    osem[sub * 2 + 1] = make_float4(sm4 * invw, sm5 * invw, sm6 * invw, sm7 * invw);
}

extern "C" void kernel_launch(void* const* d_in, const int* in_sizes, int n_in,
                              void* d_out, int out_size, void* d_ws, size_t ws_size,
                              hipStream_t stream)
{
    const float* gs_xyz     = (const float*)d_in[0];
    const float* gs_rot     = (const float*)d_in[1];
    const float* gs_scal    = (const float*)d_in[2];
    const float* gs_opa     = (const float*)d_in[3];
    const float* feat_dc    = (const float*)d_in[4];
    const float* feat_rest  = (const float*)d_in[5];
    const float* node_xyz   = (const float*)d_in[6];
    const float* node_quat  = (const float*)d_in[7];
    const float* node_sigma = (const float*)d_in[8];
    const float* node_sem   = (const float*)d_in[9];
    const int* attach_ind   = (const int*)d_in[10];
    const int* ref_time     = (const int*)d_in[11];
    const int* topo_knn     = (const int*)d_in[12];
    const int* t_ptr        = (const int*)d_in[13];

    const int N = in_sizes[0] / 3;
    const int M = in_sizes[8];                 // node_sigma is (M,1)
    const int TM = in_sizes[6] / 3;            // T*M

    float* out = (float*)d_out;

    const int block = 256;
    const int gridN = (N + block - 1) / block;
    const long long threads = (long long)N * LPG;
    const int gridM = (int)((threads + block - 1) / block);
    const int gridP = (TM + block - 1) / block;

    const size_t need_packed = (size_t)TM * 8 * sizeof(float);   // 32 B per (t,node)
    const size_t need_qb     = (size_t)N * 4 * sizeof(float);    // blended quat per gaussian

    if (ws_size >= need_packed + need_qb) {
        float* packed = (float*)d_ws;
        float* qb_ws  = (float*)d_ws + (size_t)TM * 8;
        hipLaunchKernelGGL(k_pack, dim3(gridP), dim3(block), 0, stream,
                           node_xyz, node_quat, packed, TM);
        hipLaunchKernelGGL((dynscf_kernel<true, true>), dim3(gridM), dim3(block), 0, stream,
                           gs_xyz, gs_rot, node_xyz, node_quat, packed, node_sigma, node_sem,
                           attach_ind, ref_time, topo_knn, t_ptr, out, qb_ws, N, M);
        hipLaunchKernelGGL((k_elem<true>), dim3(gridN), dim3(block), 0, stream,
                           gs_scal, gs_opa, feat_dc, feat_rest, gs_rot, node_quat,
                           attach_ind, ref_time, qb_ws, out, N, M);
    } else if (ws_size >= need_qb) {
        float* qb_ws = (float*)d_ws;
        hipLaunchKernelGGL((dynscf_kernel<false, true>), dim3(gridM), dim3(block), 0, stream,
                           gs_xyz, gs_rot, node_xyz, node_quat, (const float*)nullptr,
                           node_sigma, node_sem,
                           attach_ind, ref_time, topo_knn, t_ptr, out, qb_ws, N, M);
        hipLaunchKernelGGL((k_elem<true>), dim3(gridN), dim3(block), 0, stream,
                           gs_scal, gs_opa, feat_dc, feat_rest, gs_rot, node_quat,
                           attach_ind, ref_time, qb_ws, out, N, M);
    } else {
        hipLaunchKernelGGL((dynscf_kernel<false, false>), dim3(gridM), dim3(block), 0, stream,
                           gs_xyz, gs_rot, node_xyz, node_quat, (const float*)nullptr,
                           node_sigma, node_sem,
                           attach_ind, ref_time, topo_knn, t_ptr, out, (float*)nullptr, N, M);
        hipLaunchKernelGGL((k_elem<false>), dim3(gridN), dim3(block), 0, stream,
                           gs_scal, gs_opa, feat_dc, feat_rest, gs_rot, node_quat,
                           attach_ind, ref_time, (const float*)nullptr, out, N, M);
    }
}

// Round 2
// 215.534 us; speedup vs baseline: 1.3805x; 1.0368x over previous
//
#include <hip/hip_runtime.h>

#define KNN 16
#define FSEM 32
#define LPG 4                 // 4 lanes cooperate per gaussian
#define NXCD 8

__device__ __forceinline__ float sigmoidf_(float x) { return 1.0f / (1.0f + __expf(-x)); }

// q / clip(|q|,1e-12) -> row-major 3x3
__device__ __forceinline__ void quat_to_R(float qw, float qx, float qy, float qz, float* R) {
    float d = qw * qw + qx * qx + qy * qy + qz * qz;
    float inv = rsqrtf(fmaxf(d, 1e-24f));
    float w = qw * inv, x = qx * inv, y = qy * inv, z = qz * inv;
    R[0] = 1.f - 2.f * (y * y + z * z); R[1] = 2.f * (x * y - w * z); R[2] = 2.f * (x * z + w * y);
    R[3] = 2.f * (x * y + w * z); R[4] = 1.f - 2.f * (x * x + z * z); R[5] = 2.f * (y * z - w * x);
    R[6] = 2.f * (x * z - w * y); R[7] = 2.f * (y * z + w * x); R[8] = 1.f - 2.f * (x * x + y * y);
}

// ---- prepack: packed[p] = {x,y,z,sigma, qw,qx,qy,qz} (32 B, line-friendly).
// Also zeroes the sort histogram (B == T*M == TM, so this grid covers it). ----
__global__ void __launch_bounds__(256)
k_pack(const float* __restrict__ node_xyz, const float* __restrict__ node_quat,
       const float* __restrict__ node_sigma,
       float* __restrict__ packed, int* __restrict__ cnt, int TM, int M, int B)
{
    int p = blockIdx.x * blockDim.x + threadIdx.x;
    if (p < B && cnt) cnt[p] = 0;
    if (p >= TM) return;
    const int node = p - (p / M) * M;          // p % M
    const float* x = node_xyz + 3 * (size_t)p;
    float4 a = make_float4(x[0], x[1], x[2], node_sigma[node]);
    float4 q = reinterpret_cast<const float4*>(node_quat)[p];
    float4* dst = reinterpret_cast<float4*>(packed + 8 * (size_t)p);
    dst[0] = a;
    dst[1] = q;
}

// ---- counting sort by key = rt*M + attach ----
__global__ void __launch_bounds__(256)
k_hist(const int* __restrict__ attach, const int* __restrict__ rtime,
       int* __restrict__ cnt, int* __restrict__ rank, int N, int M)
{
    int n = blockIdx.x * blockDim.x + threadIdx.x;
    if (n >= N) return;
    const int key = rtime[n] * M + attach[n];
    rank[n] = atomicAdd(&cnt[key], 1);
}

// exclusive scan within 256-bucket blocks, in-place; block totals out.
__global__ void __launch_bounds__(256)
k_scan1(int* __restrict__ cnt, int* __restrict__ blk, int B)
{
    __shared__ int sh[256];
    const int i = blockIdx.x * 256 + threadIdx.x;
    int v = (i < B) ? cnt[i] : 0;
    sh[threadIdx.x] = v;
    __syncthreads();
    int acc = v;
#pragma unroll
    for (int off = 1; off < 256; off <<= 1) {
        int u = (threadIdx.x >= off) ? sh[threadIdx.x - off] : 0;
        __syncthreads();
        acc += u;
        sh[threadIdx.x] = acc;
        __syncthreads();
    }
    if (i < B) cnt[i] = acc - v;                 // exclusive within block
    if (threadIdx.x == 255) blk[blockIdx.x] = acc;   // block total
}

// single-block exclusive scan of block totals (nblk <= a few thousand)
__global__ void __launch_bounds__(256)
k_scan2(int* __restrict__ blk, int nblk)
{
    __shared__ int sh[256];
    __shared__ int carry_s;
    if (threadIdx.x == 0) carry_s = 0;
    __syncthreads();
    for (int base = 0; base < nblk; base += 256) {
        const int i = base + threadIdx.x;
        int v = (i < nblk) ? blk[i] : 0;
        sh[threadIdx.x] = v;
        __syncthreads();
        int acc = v;
#pragma unroll
        for (int off = 1; off < 256; off <<= 1) {
            int u = (threadIdx.x >= off) ? sh[threadIdx.x - off] : 0;
            __syncthreads();
            acc += u;
            sh[threadIdx.x] = acc;
            __syncthreads();
        }
        const int carry = carry_s;
        if (i < nblk) blk[i] = acc - v + carry;
        __syncthreads();
        if (threadIdx.x == 255) carry_s = carry + acc;
        __syncthreads();
    }
}

// meta[2*pos]   = {n, a, rt, 0} (as float bits)
// meta[2*pos+1] = {gx, gy, gz, 0}
__global__ void __launch_bounds__(256)
k_scatter(const int* __restrict__ attach, const int* __restrict__ rtime,
          const float* __restrict__ gs_xyz,
          const int* __restrict__ rank, const int* __restrict__ cnt,
          const int* __restrict__ blk, float4* __restrict__ meta, int N, int M)
{
    int n = blockIdx.x * blockDim.x + threadIdx.x;
    if (n >= N) return;
    const int a = attach[n], rt = rtime[n];
    const int key = rt * M + a;
    const int pos = cnt[key] + blk[key >> 8] + rank[n];
    meta[2 * (size_t)pos]     = make_float4(__int_as_float(n), __int_as_float(a),
                                            __int_as_float(rt), 0.f);
    meta[2 * (size_t)pos + 1] = make_float4(gs_xyz[3 * (size_t)n + 0],
                                            gs_xyz[3 * (size_t)n + 1],
                                            gs_xyz[3 * (size_t)n + 2], 0.f);
}

// ---- elementwise outputs + (optionally) the fr_live epilogue ----
template<bool FR>
__global__ void __launch_bounds__(256)
k_elem(const float* __restrict__ gs_scal,
       const float* __restrict__ gs_opa,
       const float* __restrict__ feat_dc,
       const float* __restrict__ feat_rest,
       const float* __restrict__ gs_rot,
       const float* __restrict__ node_quat,
       const int*   __restrict__ attach_ind,
       const int*   __restrict__ ref_time,
       const float* __restrict__ qb_ws,
       float* __restrict__ out, int N, int M)
{
    const int n = blockIdx.x * blockDim.x + threadIdx.x;
    if (n >= N) return;
    const size_t Ns = (size_t)N, ns = (size_t)n;

    float* os = out + 12 * Ns + 3 * ns;
    os[0] = 0.1f * sigmoidf_(gs_scal[3 * ns + 0]);
    os[1] = 0.1f * sigmoidf_(gs_scal[3 * ns + 1]);
    os[2] = 0.1f * sigmoidf_(gs_scal[3 * ns + 2]);

    out[15 * Ns + ns] = sigmoidf_(gs_opa[ns]);

    float* osph = out + 16 * Ns + 12 * ns;   // 16B-aligned
    float4 v0 = make_float4(feat_dc[3 * ns + 0], feat_dc[3 * ns + 1], feat_dc[3 * ns + 2],
                            feat_rest[9 * ns + 0]);
    float4 v1 = make_float4(feat_rest[9 * ns + 1], feat_rest[9 * ns + 2],
                            feat_rest[9 * ns + 3], feat_rest[9 * ns + 4]);
    float4 v2 = make_float4(feat_rest[9 * ns + 5], feat_rest[9 * ns + 6],
                            feat_rest[9 * ns + 7], feat_rest[9 * ns + 8]);
    reinterpret_cast<float4*>(osph)[0] = v0;
    reinterpret_cast<float4*>(osph)[1] = v1;
    reinterpret_cast<float4*>(osph)[2] = v2;

    if constexpr (FR) {
        // fr_live = q2R(qb) @ (Rref @ q2R(gs_rot)); qb already scaled by invw
        // in the main kernel (fp32 subnormal guard).
        const int a  = attach_ind[n];
        const int rt = ref_time[n];
        const float4 qa = reinterpret_cast<const float4*>(node_quat)[(size_t)rt * (size_t)M + (size_t)a];
        float Rref[9];
        quat_to_R(qa.x, qa.y, qa.z, qa.w, Rref);

        const float4 qg = reinterpret_cast<const float4*>(gs_rot)[ns];
        float Rg[9];
        quat_to_R(qg.x, qg.y, qg.z, qg.w, Rg);

        float Rw[9];
#pragma unroll
        for (int i = 0; i < 3; i++)
#pragma unroll
            for (int j = 0; j < 3; j++)
                Rw[3 * i + j] = Rref[3 * i] * Rg[j] + Rref[3 * i + 1] * Rg[3 + j] + Rref[3 * i + 2] * Rg[6 + j];

        const float4 qb = reinterpret_cast<const float4*>(qb_ws)[ns];
        float Rb[9];
        quat_to_R(qb.x, qb.y, qb.z, qb.w, Rb);

        float* ofr = out + 3 * Ns + 9 * ns;
#pragma unroll
        for (int i = 0; i < 3; i++)
#pragma unroll
            for (int j = 0; j < 3; j++)
                ofr[3 * i + j] = Rb[3 * i] * Rw[j] + Rb[3 * i + 1] * Rw[3 + j] + Rb[3 * i + 2] * Rw[6 + j];
    }
}

// ---- main skinning kernel ----
template<bool PACKED, bool FRSPLIT, bool SORTED>
__global__ void __launch_bounds__(256)
dynscf_kernel(const float* __restrict__ gs_xyz,
              const float* __restrict__ gs_rot,
              const float* __restrict__ node_xyz,
              const float* __restrict__ node_quat,
              const float* __restrict__ packed,
              const float* __restrict__ node_sigma,
              const float* __restrict__ node_sem,
              const int* __restrict__ attach_ind,
              const int* __restrict__ ref_time,
              const int* __restrict__ topo_knn,
              const int* __restrict__ t_ptr,
              const float4* __restrict__ meta,
              float* __restrict__ out,
              float* __restrict__ qb_out,
              int N, int M)
{
    int bid = blockIdx.x;
    if (SORTED) {
        // m204 bijective chunked XCD swizzle: each XCD gets a contiguous
        // range of the (rt, attach)-sorted gaussians -> its L2 holds the
        // active rt slices + sem + live slice.
        const int nwg = gridDim.x;
        const int q = nwg / NXCD, r = nwg % NXCD;
        const int xcd = bid % NXCD, idx = bid / NXCD;
        bid = (xcd < r ? xcd * (q + 1) : r * (q + 1) + (xcd - r) * q) + idx;
    }
    const int tid = bid * blockDim.x + threadIdx.x;
    const int g   = tid >> 2;            // sorted-order group index
    const int sub = tid & (LPG - 1);
    if (g >= N) return;

    const int t = t_ptr[0];

    int n, a, rt;
    float gx, gy, gz;
    if (SORTED) {
        const float4 m0 = meta[2 * (size_t)g];
        const float4 m1 = meta[2 * (size_t)g + 1];
        n  = __float_as_int(m0.x);
        a  = __float_as_int(m0.y);
        rt = __float_as_int(m0.z);
        gx = m1.x; gy = m1.y; gz = m1.z;
    } else {
        n  = g;
        a  = attach_ind[n];
        rt = ref_time[n];
        gx = gs_xyz[3 * (size_t)n + 0];
        gy = gs_xyz[3 * (size_t)n + 1];
        gz = gs_xyz[3 * (size_t)n + 2];
    }

    const size_t base_rt = (size_t)rt * (size_t)M;
    const size_t base_t  = (size_t)t  * (size_t)M;

    // neighbor indices first so downstream gather addresses are known early
    const int4 kv = reinterpret_cast<const int4*>(topo_knn)[(size_t)a * (KNN / 4) + sub];
    const int js[4] = { kv.x, kv.y, kv.z, kv.w };

    // --- attach node @ ref time ---
    float apx, apy, apz, aqw, aqx, aqy, aqz;
    if (PACKED) {
        const float4* pk = reinterpret_cast<const float4*>(packed + (base_rt + (size_t)a) * 8);
        float4 xz = pk[0], qv = pk[1];
        apx = xz.x; apy = xz.y; apz = xz.z;
        aqw = qv.x; aqx = qv.y; aqy = qv.z; aqz = qv.w;
    } else {
        const float4 qv = *reinterpret_cast<const float4*>(node_quat + (base_rt + (size_t)a) * 4);
        const float* pa = node_xyz + (base_rt + (size_t)a) * 3;
        apx = pa[0]; apy = pa[1]; apz = pa[2];
        aqw = qv.x; aqx = qv.y; aqy = qv.z; aqz = qv.w;
    }
    float Rref[9];
    quat_to_R(aqw, aqx, aqy, aqz, Rref);

    const float xw0 = Rref[0] * gx + Rref[1] * gy + Rref[2] * gz + apx;
    const float xw1 = Rref[3] * gx + Rref[4] * gy + Rref[5] * gz + apy;
    const float xw2 = Rref[6] * gx + Rref[7] * gy + Rref[8] * gz + apz;
    // NOTE: in FRSPLIT mode Rref is dead from here on (k_elem recomputes it).

    float wsum = 0.f, mu0 = 0.f, mu1 = 0.f, mu2 = 0.f;
    float qb0 = 0.f, qb1 = 0.f, qb2 = 0.f, qb3 = 0.f;
    float wk[4];

#pragma unroll
    for (int k = 0; k < KNN / LPG; k++) {
        const int j = js[k];

        float prx, pry, prz, rw, rx, ry, rz;
        float plx, ply, plz, lw, lx, ly, lz;
        float sg;
        if (PACKED) {
            const float4* pkr = reinterpret_cast<const float4*>(packed + (base_rt + (size_t)j) * 8);
            float4 xr = pkr[0], qr = pkr[1];
            prx = xr.x; pry = xr.y; prz = xr.z; sg = xr.w;
            rw = qr.x; rx = qr.y; ry = qr.z; rz = qr.w;
            const float4* pkl = reinterpret_cast<const float4*>(packed + (base_t + (size_t)j) * 8);
            float4 xl = pkl[0], ql = pkl[1];
            plx = xl.x; ply = xl.y; plz = xl.z;
            lw = ql.x; lx = ql.y; ly = ql.z; lz = ql.w;
        } else {
            const float* pr = node_xyz + (base_rt + (size_t)j) * 3;
            prx = pr[0]; pry = pr[1]; prz = pr[2];
            const float4 qr = *reinterpret_cast<const float4*>(node_quat + (base_rt + (size_t)j) * 4);
            rw = qr.x; rx = qr.y; ry = qr.z; rz = qr.w;
            const float* pl = node_xyz + (base_t + (size_t)j) * 3;
            plx = pl[0]; ply = pl[1]; plz = pl[2];
            const float4 ql = *reinterpret_cast<const float4*>(node_quat + (base_t + (size_t)j) * 4);
            lw = ql.x; lx = ql.y; ly = ql.z; lz = ql.w;
            sg = node_sigma[j];
        }

        const float dx = xw0 - prx;
        const float dy = xw1 - pry;
        const float dz = xw2 - prz;
        const float dsq = dx * dx + dy * dy + dz * dz;

        const float w = __expf(-dsq / (2.f * sg * sg + 1e-8f));
        wk[k] = w;

        {
            float inv = rsqrtf(fmaxf(rw * rw + rx * rx + ry * ry + rz * rz, 1e-24f));
            rw *= inv; rx *= inv; ry *= inv; rz *= inv;
        }
        {
            float inv = rsqrtf(fmaxf(lw * lw + lx * lx + ly * ly + lz * lz, 1e-24f));
            lw *= inv; lx *= inv; ly *= inv; lz *= inv;
        }
        // q_rel = q_live * conj(q_ref)
        const float qw =  lw * rw + lx * rx + ly * ry + lz * rz;
        const float qx = -lw * rx + lx * rw - ly * rz + lz * ry;
        const float qy = -lw * ry + lx * rz + ly * rw - lz * rx;
        const float qz = -lw * rz - lx * ry + ly * rx + lz * rw;

        float Rr[9];
        quat_to_R(qw, qx, qy, qz, Rr);

        const float m0 = Rr[0] * dx + Rr[1] * dy + Rr[2] * dz + plx;
        const float m1 = Rr[3] * dx + Rr[4] * dy + Rr[5] * dz + ply;
        const float m2 = Rr[6] * dx + Rr[7] * dy + Rr[8] * dz + plz;

        wsum += w;
        mu0 += w * m0; mu1 += w * m1; mu2 += w * m2;
        qb0 += w * qw; qb1 += w * qx; qb2 += w * qy; qb3 += w * qz;
    }

    // group-reduce the 8 scalar accumulators (2 rounds within the 4-lane group)
#pragma unroll
    for (int m = 1; m < LPG; m <<= 1) {
        wsum += __shfl_xor(wsum, m);
        mu0  += __shfl_xor(mu0, m);  mu1 += __shfl_xor(mu1, m);  mu2 += __shfl_xor(mu2, m);
        qb0  += __shfl_xor(qb0, m);  qb1 += __shfl_xor(qb1, m);
        qb2  += __shfl_xor(qb2, m);  qb3 += __shfl_xor(qb3, m);
    }

    const float invw = 1.f / (wsum + 1e-8f);
    const size_t Ns = (size_t)N, ns = (size_t)n;

    // --- sem: feature-sliced. Lane `sub` owns features [8*sub, 8*sub+8) and
    // walks all 16 neighbors, pulling (j, w) from the owning lane via shfl. ---
    float sm0 = 0.f, sm1 = 0.f, sm2 = 0.f, sm3 = 0.f;
    float sm4 = 0.f, sm5 = 0.f, sm6 = 0.f, sm7 = 0.f;
    const float4* sem4 = reinterpret_cast<const float4*>(node_sem);
#pragma unroll
    for (int kk = 0; kk < KNN; kk++) {
        const int src = kk >> 2;        // lane within group that owns this neighbor
        const int idx = kk & 3;         // compile-time (loop fully unrolled)
        const int   jk = __shfl(js[idx], src, LPG);
        const float wkk = __shfl(wk[idx], src, LPG);
        const float4 v0 = sem4[(size_t)jk * (FSEM / 4) + sub * 2 + 0];
        const float4 v1 = sem4[(size_t)jk * (FSEM / 4) + sub * 2 + 1];
        sm0 += wkk * v0.x; sm1 += wkk * v0.y; sm2 += wkk * v0.z; sm3 += wkk * v0.w;
        sm4 += wkk * v1.x; sm5 += wkk * v1.y; sm6 += wkk * v1.z; sm7 += wkk * v1.w;
    }

    if (sub == 0) {
        out[3 * ns + 0] = mu0 * invw;
        out[3 * ns + 1] = mu1 * invw;
        out[3 * ns + 2] = mu2 * invw;
    } else if (sub == 1) {
        if (FRSPLIT) {
            reinterpret_cast<float4*>(qb_out)[ns] =
                make_float4(qb0 * invw, qb1 * invw, qb2 * invw, qb3 * invw);
        }
    }

    if constexpr (!FRSPLIT) {
        if (sub == 1) {
            // fr_live = q2R(qb*invw) @ (Rref @ q2R(gs_rot)); invw BEFORE q2R (fp32
            // subnormal guard — r5 bug).
            const float4 qg = *reinterpret_cast<const float4*>(gs_rot + 4 * ns);
            float Rg[9];
            quat_to_R(qg.x, qg.y, qg.z, qg.w, Rg);
            float Rw[9];
#pragma unroll
            for (int i = 0; i < 3; i++)
#pragma unroll
                for (int j = 0; j < 3; j++)
                    Rw[3 * i + j] = Rref[3 * i] * Rg[j] + Rref[3 * i + 1] * Rg[3 + j] + Rref[3 * i + 2] * Rg[6 + j];
            float Rb[9];
            quat_to_R(qb0 * invw, qb1 * invw, qb2 * invw, qb3 * invw, Rb);
            float* ofr = out + 3 * Ns + 9 * ns;
#pragma unroll
            for (int i = 0; i < 3; i++)
#pragma unroll
                for (int j = 0; j < 3; j++)
                    ofr[3 * i + j] = Rb[3 * i] * Rw[j] + Rb[3 * i + 1] * Rw[3 + j] + Rb[3 * i + 2] * Rw[6 + j];
        }
    }

    // sem_live: [28N, 60N); lane writes its own 2 float4s (one 128 B line/gaussian)
    float4* osem = reinterpret_cast<float4*>(out + 28 * Ns + FSEM * ns);
    osem[sub * 2 + 0] = make_float4(sm0 * invw, sm1 * invw, sm2 * invw, sm3 * invw);
    osem[sub * 2 + 1] = make_float4(sm4 * invw, sm5 * invw, sm6 * invw, sm7 * invw);
}

extern "C" void kernel_launch(void* const* d_in, const int* in_sizes, int n_in,
                              void* d_out, int out_size, void* d_ws, size_t ws_size,
                              hipStream_t stream)
{
    const float* gs_xyz     = (const float*)d_in[0];
    const float* gs_rot     = (const float*)d_in[1];
    const float* gs_scal    = (const float*)d_in[2];
    const float* gs_opa     = (const float*)d_in[3];
    const float* feat_dc    = (const float*)d_in[4];
    const float* feat_rest  = (const float*)d_in[5];
    const float* node_xyz   = (const float*)d_in[6];
    const float* node_quat  = (const float*)d_in[7];
    const float* node_sigma = (const float*)d_in[8];
    const float* node_sem   = (const float*)d_in[9];
    const int* attach_ind   = (const int*)d_in[10];
    const int* ref_time     = (const int*)d_in[11];
    const int* topo_knn     = (const int*)d_in[12];
    const int* t_ptr        = (const int*)d_in[13];

    const int N = in_sizes[0] / 3;
    const int M = in_sizes[8];                 // node_sigma is (M,1)
    const int TM = in_sizes[6] / 3;            // T*M
    const int B  = TM;                         // sort buckets: key = rt*M + a

    float* out = (float*)d_out;

    const int block = 256;
    const int gridN = (N + block - 1) / block;
    const long long threads = (long long)N * LPG;
    const int gridM = (int)((threads + block - 1) / block);
    const int gridP = (TM + block - 1) / block;
    const int nblkS = (B + 255) / 256;

    // workspace layout (floats): packed | qb | meta(2*float4/gauss) | cnt | blk
    // rank aliases qb (qb written only by main kernel, after scatter consumed rank)
    const size_t f_packed = (size_t)TM * 8;
    const size_t f_qb     = (size_t)N * 4;
    const size_t f_meta   = (size_t)N * 8;
    const size_t i_cnt    = (size_t)B;
    const size_t i_blk    = 4096;
    const size_t need_sort   = (f_packed + f_qb + f_meta + i_cnt + i_blk) * sizeof(float);
    const size_t need_packed = (f_packed + f_qb) * sizeof(float);
    const size_t need_qb     = f_qb * sizeof(float);

    if (ws_size >= need_sort && nblkS <= 4096) {
        float*  packed = (float*)d_ws;
        float*  qb_ws  = packed + f_packed;
        float4* meta   = (float4*)(packed + f_packed + f_qb);
        int*    cnt    = (int*)(packed + f_packed + f_qb + f_meta);
        int*    blk    = cnt + i_cnt;
        int*    rank   = (int*)qb_ws;

        hipLaunchKernelGGL(k_pack, dim3(gridP), dim3(block), 0, stream,
                           node_xyz, node_quat, node_sigma, packed, cnt, TM, M, B);
        hipLaunchKernelGGL(k_hist, dim3(gridN), dim3(block), 0, stream,
                           attach_ind, ref_time, cnt, rank, N, M);
        hipLaunchKernelGGL(k_scan1, dim3(nblkS), dim3(block), 0, stream,
                           cnt, blk, B);
        hipLaunchKernelGGL(k_scan2, dim3(1), dim3(block), 0, stream,
                           blk, nblkS);
        hipLaunchKernelGGL(k_scatter, dim3(gridN), dim3(block), 0, stream,
                           attach_ind, ref_time, gs_xyz, rank, cnt, blk, meta, N, M);
        hipLaunchKernelGGL((dynscf_kernel<true, true, true>), dim3(gridM), dim3(block), 0, stream,
                           gs_xyz, gs_rot, node_xyz, node_quat, packed, node_sigma, node_sem,
                           attach_ind, ref_time, topo_knn, t_ptr, meta, out, qb_ws, N, M);
        hipLaunchKernelGGL((k_elem<true>), dim3(gridN), dim3(block), 0, stream,
                           gs_scal, gs_opa, feat_dc, feat_rest, gs_rot, node_quat,
                           attach_ind, ref_time, qb_ws, out, N, M);
    } else if (ws_size >= need_packed) {
        float* packed = (float*)d_ws;
        float* qb_ws  = packed + f_packed;
        hipLaunchKernelGGL(k_pack, dim3(gridP), dim3(block), 0, stream,
                           node_xyz, node_quat, node_sigma, packed, (int*)nullptr, TM, M, 0);
        hipLaunchKernelGGL((dynscf_kernel<true, true, false>), dim3(gridM), dim3(block), 0, stream,
                           gs_xyz, gs_rot, node_xyz, node_quat, packed, node_sigma, node_sem,
                           attach_ind, ref_time, topo_knn, t_ptr, (const float4*)nullptr,
                           out, qb_ws, N, M);
        hipLaunchKernelGGL((k_elem<true>), dim3(gridN), dim3(block), 0, stream,
                           gs_scal, gs_opa, feat_dc, feat_rest, gs_rot, node_quat,
                           attach_ind, ref_time, qb_ws, out, N, M);
    } else if (ws_size >= need_qb) {
        float* qb_ws = (float*)d_ws;
        hipLaunchKernelGGL((dynscf_kernel<false, true, false>), dim3(gridM), dim3(block), 0, stream,
                           gs_xyz, gs_rot, node_xyz, node_quat, (const float*)nullptr,
                           node_sigma, node_sem,
                           attach_ind, ref_time, topo_knn, t_ptr, (const float4*)nullptr,
                           out, qb_ws, N, M);
        hipLaunchKernelGGL((k_elem<true>), dim3(gridN), dim3(block), 0, stream,
                           gs_scal, gs_opa, feat_dc, feat_rest, gs_rot, node_quat,
                           attach_ind, ref_time, qb_ws, out, N, M);
    } else {
        hipLaunchKernelGGL((dynscf_kernel<false, false, false>), dim3(gridM), dim3(block), 0, stream,
                           gs_xyz, gs_rot, node_xyz, node_quat, (const float*)nullptr,
                           node_sigma, node_sem,
                           attach_ind, ref_time, topo_knn, t_ptr, (const float4*)nullptr,
                           out, (float*)nullptr, N, M);
        hipLaunchKernelGGL((k_elem<false>), dim3(gridN), dim3(block), 0, stream,
                           gs_scal, gs_opa, feat_dc, feat_rest, gs_rot, node_quat,
                           attach_ind, ref_time, (const float*)nullptr, out, N, M);
    }
}